// Round 4
// baseline (1566.070 us; speedup 1.0000x reference)
//
#include <hip/hip_runtime.h>

// Forward bilinear warp (splat) via LDS privatization, channel-grouped,
// atomic-free flush (core -> direct store, halo -> private buffer + gather).
// THIS ROUND: all fp atomics use unsafeAtomicAdd -> native ds_add_f32 /
// global_atomic_add_f32 instead of the compiler's safe CAS-loop expansion.
//
//   im0:  [B, C, H, W] fp32
//   flow: [B, H, W, 2] fp32 (dx, dy)
//   out:  [B, C, H, W] fp32

#define TS   80
#define R    8
#define WIN  96             // TS + 2R
#define CG   4              // channels per block
#define NCG  8              // C / CG
#define NT1  1024
#define TILES_X 11          // ceil(854/80)
#define TILES_Y 6           // 480/80
#define NTILES (TILES_X * TILES_Y)
#define HALO_CELLS 2816     // WIN*WIN - TS*TS
#define B_  4
#define C_  32
#define H_  480
#define W_  854

// Native HW fp atomics (ds_add_f32 / global_atomic_add_f32). HIP's plain
// atomicAdd(float*) lowers to a CAS retry loop (safe-fp-atomics default),
// measured ~210 cy per LDS atomic in rounds 0-3.
__device__ __forceinline__ void fadd_lds(float* p, float v)  { unsafeAtomicAdd(p, v); }
__device__ __forceinline__ void fadd_glb(float* p, float v)  { unsafeAtomicAdd(p, v); }

// halo strip layout: [0,768): top R x WIN ; [768,1536): bottom R x WIN ;
// [1536,2176): left TS x R ; [2176,2816): right TS x R
__device__ __forceinline__ int halo_cell(int wy, int wx) {
    if (wy < R)       return wy * WIN + wx;
    if (wy >= TS + R) return R * WIN + (wy - (TS + R)) * WIN + wx;
    if (wx < R)       return 2 * R * WIN + (wy - R) * R + wx;
    return 2 * R * WIN + TS * R + (wy - R) * R + (wx - (TS + R));
}

template <bool USE_BUF>
__global__ __launch_bounds__(NT1)
void fw_warp_tiled(const float* __restrict__ im0,
                   const float* __restrict__ flow,
                   float* __restrict__ out,
                   float* __restrict__ buf) {
    const int C = C_, H = H_, W = W_;
    const int HW = H * W;
    __shared__ float acc[CG * WIN * WIN];   // 147,456 B -> 1 block/CU

    const int cg = blockIdx.x;              // channel group 0..7
    const int tI = blockIdx.y;              // tile 0..65
    const int b  = blockIdx.z;
    const int tx0 = (tI % TILES_X) * TS;
    const int ty0 = (tI / TILES_X) * TS;
    const int tid = threadIdx.x;

    for (int i = tid; i < CG * WIN * WIN; i += NT1) acc[i] = 0.0f;
    __syncthreads();

    const float*  imp = im0 + (size_t)(b * C + cg * CG) * HW;
    const float2* flp = (const float2*)flow + (size_t)b * HW;

    for (int i = tid; i < TS * TS; i += NT1) {
        int py = i / TS, px = i - py * TS;
        int y = ty0 + py, x = tx0 + px;
        if (x >= W) continue;               // partial right-edge tile
        float2 f = flp[y * W + x];
        float xf = (float)x + f.x;
        float yf = (float)y + f.y;
        float x0f = floorf(xf), y0f = floorf(yf);
        int x0 = (int)x0f, y0 = (int)y0f;
        // both corners (x0, x0+1) must be inside the LDS window
        if (x0 < tx0 - R || x0 > tx0 + TS + R - 2 ||
            y0 < ty0 - R || y0 > ty0 + TS + R - 2) continue;  // far kernel
        float wx1 = xf - x0f, wx0 = 1.0f - wx1;
        float wy1 = yf - y0f, wy0 = 1.0f - wy1;
        float w00 = wx0 * wy0, w10 = wx1 * wy0;
        float w01 = wx0 * wy1, w11 = wx1 * wy1;

        const float* ip = imp + (size_t)y * W + x;
        float v0 = ip[0];
        float v1 = ip[HW];
        float v2 = ip[2 * HW];
        float v3 = ip[3 * HW];

        int lx = x0 - (tx0 - R);
        int ly = y0 - (ty0 - R);
        float* p = &acc[ly * WIN + lx];
        fadd_lds(p,           v0 * w00);
        fadd_lds(p + 1,       v0 * w10);
        fadd_lds(p + WIN,     v0 * w01);
        fadd_lds(p + WIN + 1, v0 * w11);
        p += WIN * WIN;
        fadd_lds(p,           v1 * w00);
        fadd_lds(p + 1,       v1 * w10);
        fadd_lds(p + WIN,     v1 * w01);
        fadd_lds(p + WIN + 1, v1 * w11);
        p += WIN * WIN;
        fadd_lds(p,           v2 * w00);
        fadd_lds(p + 1,       v2 * w10);
        fadd_lds(p + WIN,     v2 * w01);
        fadd_lds(p + WIN + 1, v2 * w11);
        p += WIN * WIN;
        fadd_lds(p,           v3 * w00);
        fadd_lds(p + 1,       v3 * w10);
        fadd_lds(p + WIN,     v3 * w01);
        fadd_lds(p + WIN + 1, v3 * w11);
    }
    __syncthreads();

    float* outp = out + (size_t)(b * C + cg * CG) * HW;

    if (USE_BUF) {
        // core: every tile pixel written exactly once by this block (no memset,
        // no atomics). Ring/halo contributions arrive later via gather+far.
        for (int i = tid; i < TS * TS; i += NT1) {
            int py = i / TS, px = i - py * TS;
            int gx = tx0 + px;
            if (gx >= W_) continue;
            size_t o = (size_t)(ty0 + py) * W_ + gx;
            #pragma unroll
            for (int c = 0; c < CG; ++c)
                outp[(size_t)c * HW + o] = acc[(c * WIN + (R + py)) * WIN + (R + px)];
        }
        // halo frame -> private buffer (plain stores, dense, incl. zeros)
        float* bufp = buf + ((size_t)(b * C + cg * CG) * NTILES + tI) * HALO_CELLS;
        for (int i = tid; i < HALO_CELLS; i += NT1) {
            int wy, wx;
            if (i < R * WIN)            { wy = i / WIN;                 wx = i % WIN; }
            else if (i < 2 * R * WIN)   { int j = i - R * WIN;          wy = TS + R + j / WIN; wx = j % WIN; }
            else if (i < 2 * R * WIN + TS * R) { int j = i - 2 * R * WIN; wy = R + j / R; wx = j % R; }
            else                        { int j = i - 2 * R * WIN - TS * R; wy = R + j / R; wx = TS + R + j % R; }
            #pragma unroll
            for (int c = 0; c < CG; ++c)
                bufp[(size_t)c * NTILES * HALO_CELLS + i] = acc[(c * WIN + wy) * WIN + wx];
        }
    } else {
        // fallback (ws too small): atomic ring flush; out pre-zeroed.
        for (int i = tid; i < WIN * WIN; i += NT1) {
            int wy = i / WIN, wx = i - wy * WIN;
            int gy = ty0 - R + wy;
            int gx = tx0 - R + wx;
            if ((unsigned)gy < (unsigned)H_ && (unsigned)gx < (unsigned)W_) {
                bool interior = (wy >= 2 * R) && (wy < TS) && (wx >= 2 * R) && (wx < TS);
                size_t o = (size_t)gy * W_ + gx;
                #pragma unroll
                for (int c = 0; c < CG; ++c) {
                    float v = acc[c * WIN * WIN + i];
                    if (interior)          outp[(size_t)c * HW + o] = v;
                    else if (v != 0.0f)    fadd_glb(&outp[(size_t)c * HW + o], v);
                }
            }
        }
    }
}

// Gather pass: each ring pixel sums the <=3 neighbor-tile halo cells that
// cover it. One owner thread per (b,y,x), all C channels -> no atomics.
__global__ __launch_bounds__(256)
void fw_warp_gather(const float* __restrict__ buf, float* __restrict__ out) {
    int tid = blockIdx.x * 256 + threadIdx.x;
    const int total = B_ * H_ * W_;
    if (tid >= total) return;
    int x = tid % W_;
    int t = tid / W_;
    int y = t % H_;
    int b = t / H_;
    int tx = x / TS, ty = y / TS;
    int px = x - tx * TS, py = y - ty * TS;
    bool rl = px < R, rr = px >= TS - R;
    bool rt = py < R, rb = py >= TS - R;
    if (!(rl | rr | rt | rb)) return;

    int dx = rl ? -1 : (rr ? 1 : 0);
    int dy = rt ? -1 : (rb ? 1 : 0);

    int t_h = -1, c_h = 0, t_v = -1, c_v = 0, t_d = -1, c_d = 0;
    if (dx) {
        int ntx = tx + dx;
        if ((unsigned)ntx < TILES_X) {
            t_h = ty * TILES_X + ntx;
            c_h = halo_cell(y - (ty * TS - R), x - (ntx * TS - R));
        }
    }
    if (dy) {
        int nty = ty + dy;
        if ((unsigned)nty < TILES_Y) {
            t_v = nty * TILES_X + tx;
            c_v = halo_cell(y - (nty * TS - R), x - (tx * TS - R));
        }
    }
    if (dx && dy) {
        int ntx = tx + dx, nty = ty + dy;
        if ((unsigned)ntx < TILES_X && (unsigned)nty < TILES_Y) {
            t_d = nty * TILES_X + ntx;
            c_d = halo_cell(y - (nty * TS - R), x - (ntx * TS - R));
        }
    }
    if (t_h < 0 && t_v < 0 && t_d < 0) return;

    const size_t HW = (size_t)H_ * W_;
    size_t o = (size_t)y * W_ + x;
    for (int c = 0; c < C_; ++c) {
        size_t cb = (size_t)(b * C_ + c);
        float s = out[cb * HW + o];
        if (t_h >= 0) s += buf[(cb * NTILES + t_h) * HALO_CELLS + c_h];
        if (t_v >= 0) s += buf[(cb * NTILES + t_v) * HALO_CELLS + c_v];
        if (t_d >= 0) s += buf[(cb * NTILES + t_d) * HALO_CELLS + c_d];
        out[cb * HW + o] = s;
    }
}

// Far kernel: replay pixels whose splat window check failed, global atomics.
// Must use the SAME TS/R/window predicate as the tiled kernel. Runs last.
__global__ __launch_bounds__(256)
void fw_warp_far(const float* __restrict__ im0,
                 const float* __restrict__ flow,
                 float* __restrict__ out) {
    const int C = C_, H = H_, W = W_;
    int tid = blockIdx.x * blockDim.x + threadIdx.x;
    const int total = B_ * H * W;
    if (tid >= total) return;
    int x = tid % W;
    int t = tid / W;
    int y = t % H;
    int b = t / H;

    float2 f = ((const float2*)flow)[tid];
    float xf = (float)x + f.x;
    float yf = (float)y + f.y;
    float x0f = floorf(xf), y0f = floorf(yf);
    int x0 = (int)x0f, y0 = (int)y0f;
    int tx0 = (x / TS) * TS;
    int ty0 = (y / TS) * TS;
    bool inwin = !(x0 < tx0 - R || x0 > tx0 + TS + R - 2 ||
                   y0 < ty0 - R || y0 > ty0 + TS + R - 2);
    if (inwin) return;   // tiled kernel handled it

    float wx1 = xf - x0f, wx0 = 1.0f - wx1;
    float wy1 = yf - y0f, wy0 = 1.0f - wy1;
    bool xv0 = (unsigned)x0       < (unsigned)W;
    bool xv1 = (unsigned)(x0 + 1) < (unsigned)W;
    bool yv0 = (unsigned)y0       < (unsigned)H;
    bool yv1 = (unsigned)(y0 + 1) < (unsigned)H;

    for (int c = 0; c < C; ++c) {
        float v = im0[(((size_t)(b * C + c)) * H + y) * W + x];
        float* op = out + ((size_t)(b * C + c) * H) * W;
        if (yv0 && xv0) fadd_glb(&op[(size_t)y0 * W + x0],           v * wx0 * wy0);
        if (yv0 && xv1) fadd_glb(&op[(size_t)y0 * W + x0 + 1],       v * wx1 * wy0);
        if (yv1 && xv0) fadd_glb(&op[(size_t)(y0 + 1) * W + x0],     v * wx0 * wy1);
        if (yv1 && xv1) fadd_glb(&op[(size_t)(y0 + 1) * W + x0 + 1], v * wx1 * wy1);
    }
}

extern "C" void kernel_launch(void* const* d_in, const int* in_sizes, int n_in,
                              void* d_out, int out_size, void* d_ws, size_t ws_size,
                              hipStream_t stream) {
    const float* im0  = (const float*)d_in[0];
    const float* flow = (const float*)d_in[1];
    float* out = (float*)d_out;

    const size_t need = (size_t)B_ * C_ * NTILES * HALO_CELLS * sizeof(float); // 95.2 MB
    const int totalPix = B_ * H_ * W_;
    dim3 grid1(NCG, NTILES, B_);

    if (d_ws != nullptr && ws_size >= need) {
        // atomic-free flush path: cores cover every out pixel (no memset)
        fw_warp_tiled<true><<<grid1, NT1, 0, stream>>>(im0, flow, out, (float*)d_ws);
        fw_warp_gather<<<(totalPix + 255) / 256, 256, 0, stream>>>((const float*)d_ws, out);
    } else {
        hipMemsetAsync(d_out, 0, (size_t)out_size * sizeof(float), stream);
        fw_warp_tiled<false><<<grid1, NT1, 0, stream>>>(im0, flow, out, nullptr);
    }
    fw_warp_far<<<(totalPix + 255) / 256, 256, 0, stream>>>(im0, flow, out);
}

// Round 5
// 1226.835 us; speedup vs baseline: 1.2765x; 1.2765x over previous
//
#include <hip/hip_runtime.h>

// Forward bilinear warp (splat) -- tile-local BIN + GATHER formulation.
//   im0:  [B, C, H, W] fp32 ; flow: [B, H, W, 2] fp32 ; out: [B, C, H, W] fp32
//
// Rounds 0-4 established: the splat loop is bound by LDS fp-atomic throughput
// (~3.3 cy/lane, invariant across structure/occupancy/unsafeAtomicAdd).
// This version eliminates fp LDS atomics: pixels are binned by NW corner cell
// (1 int LDS atomic per pixel, 16x fewer lane-atomics), then one thread per
// output cell gathers its <=4 bins' contributors and sums in registers.
// Core cells -> plain store; halo cells -> private buffer + halo-gather pass;
// window-miss pixels -> far kernel; bin-overflow pixels -> replay kernel.

#define TS   80
#define R    8
#define WIN  96             // TS + 2R
#define CG   4              // channels per block
#define NCG  8              // C / CG
#define NT1  1024
#define TILES_X 11          // ceil(854/80)
#define TILES_Y 6           // 480/80
#define NTILES (TILES_X * TILES_Y)
#define HALO_CELLS 2816     // WIN*WIN - TS*TS
#define NBIN (WIN * WIN)    // 9216 bins (NW corner cells)
#define K    6              // bin capacity (P(Poisson(0.69)>6) ~ 3.5e-5)
#define B_  4
#define C_  32
#define H_  480
#define W_  854
#define HW_ (H_ * W_)

__device__ __forceinline__ void fadd_glb(float* p, float v) { unsafeAtomicAdd(p, v); }

// halo strip layout: [0,768): top R x WIN ; [768,1536): bottom R x WIN ;
// [1536,2176): left TS x R ; [2176,2816): right TS x R
__device__ __forceinline__ int halo_cell(int wy, int wx) {
    if (wy < R)       return wy * WIN + wx;
    if (wy >= TS + R) return R * WIN + (wy - (TS + R)) * WIN + wx;
    if (wx < R)       return 2 * R * WIN + (wy - R) * R + wx;
    return 2 * R * WIN + TS * R + (wy - R) * R + (wx - (TS + R));
}

__global__ __launch_bounds__(NT1)
void fw_warp_bin(const float* __restrict__ im0,
                 const float* __restrict__ flow,
                 float* __restrict__ out,
                 float* __restrict__ buf,
                 unsigned* __restrict__ ovctr,
                 unsigned* __restrict__ ovlist,
                 unsigned cap) {
    __shared__ unsigned short bins[NBIN * K];   // 110,592 B
    __shared__ unsigned       cnts[NBIN];       //  36,864 B (total 147,456)

    const int cg = blockIdx.x;              // channel group 0..7
    const int tI = blockIdx.y;              // tile 0..65
    const int b  = blockIdx.z;
    const int tx0 = (tI % TILES_X) * TS;
    const int ty0 = (tI / TILES_X) * TS;
    const int tid = threadIdx.x;

    for (int i = tid; i < NBIN; i += NT1) cnts[i] = 0u;
    __syncthreads();

    const float*  imp = im0 + (size_t)(b * C_ + cg * CG) * HW_;
    const float2* flp = (const float2*)flow + (size_t)b * HW_;

    // ---- phase 1: bin pixels by NW corner cell (1 int atomic per pixel) ----
    for (int i = tid; i < TS * TS; i += NT1) {
        int py = i / TS, px = i - py * TS;
        int y = ty0 + py, x = tx0 + px;
        if (x >= W_) continue;              // partial right-edge tile
        float2 f = flp[y * W_ + x];
        float xf = (float)x + f.x;
        float yf = (float)y + f.y;
        float x0f = floorf(xf), y0f = floorf(yf);
        int x0 = (int)x0f, y0 = (int)y0f;
        // both corners must be inside the LDS window (same predicate as far)
        if (x0 < tx0 - R || x0 > tx0 + TS + R - 2 ||
            y0 < ty0 - R || y0 > ty0 + TS + R - 2) continue;   // far kernel
        int bin = (y0 - (ty0 - R)) * WIN + (x0 - (tx0 - R));
        unsigned slot = atomicAdd(&cnts[bin], 1u);              // ds_add_rtn_u32
        if (slot < K) {
            bins[bin * K + slot] = (unsigned short)i;
        } else {
            // overflow: replay later with global atomics (per-cg entry so all
            // 8 cg-blocks stay consistent despite order-dependent slots)
            unsigned gid = (unsigned)(b * HW_ + y * W_ + x);    // < 2^24
            unsigned idx = atomicAdd(ovctr, 1u);
            if (idx < cap) ovlist[idx] = ((unsigned)cg << 24) | gid;
        }
    }
    __syncthreads();

    // ---- phase 2: per-cell gather + direct flush ----
    float* outp = out + (size_t)(b * C_ + cg * CG) * HW_;
    float* bufp = buf + ((size_t)(b * C_ + cg * CG) * NTILES + tI) * HALO_CELLS;
    for (int i = tid; i < WIN * WIN; i += NT1) {
        int wy = i / WIN, wx = i - wy * WIN;
        float s0 = 0.f, s1 = 0.f, s2 = 0.f, s3 = 0.f;
        #pragma unroll
        for (int a = 0; a < 2; ++a) {           // NW row: wy-a
            int by = wy - a;
            if (by < 0) continue;
            #pragma unroll
            for (int bxo = 0; bxo < 2; ++bxo) { // NW col: wx-bxo
                int bx = wx - bxo;
                if (bx < 0) continue;
                int bin = by * WIN + bx;
                unsigned cnt = cnts[bin]; if (cnt > K) cnt = K;
                for (unsigned j = 0; j < cnt; ++j) {
                    int id = bins[bin * K + j];
                    int ppy = id / TS, ppx = id - ppy * TS;
                    int gy = ty0 + ppy, gx = tx0 + ppx;
                    float2 f = flp[gy * W_ + gx];
                    float xf = (float)gx + f.x;
                    float yf = (float)gy + f.y;
                    float fx = xf - floorf(xf);
                    float fy = yf - floorf(yf);
                    float wgt = (bxo ? fx : 1.0f - fx) * (a ? fy : 1.0f - fy);
                    const float* ip = imp + (size_t)gy * W_ + gx;
                    s0 += ip[0]          * wgt;
                    s1 += ip[HW_]        * wgt;
                    s2 += ip[2 * HW_]    * wgt;
                    s3 += ip[3 * HW_]    * wgt;
                }
            }
        }
        int gy = ty0 - R + wy, gx = tx0 - R + wx;
        bool core = (wy >= R) && (wy < TS + R) && (wx >= R) && (wx < TS + R);
        if (core) {
            if (gx < W_) {                      // gy in range by construction
                size_t o = (size_t)gy * W_ + gx;
                outp[o]                  = s0;
                outp[(size_t)HW_ + o]    = s1;
                outp[2 * (size_t)HW_ + o] = s2;
                outp[3 * (size_t)HW_ + o] = s3;
            }
        } else {
            int hc = halo_cell(wy, wx);
            bufp[hc]                                   = s0;
            bufp[(size_t)NTILES * HALO_CELLS + hc]     = s1;
            bufp[2 * (size_t)NTILES * HALO_CELLS + hc] = s2;
            bufp[3 * (size_t)NTILES * HALO_CELLS + hc] = s3;
        }
    }
}

// Halo-gather: each ring pixel sums the <=3 neighbor-tile halo cells covering
// it. Parallel over (pixel, channel-group): 8x threads vs old version for MLP.
__global__ __launch_bounds__(256)
void fw_warp_hgather(const float* __restrict__ buf, float* __restrict__ out) {
    int t = blockIdx.x * 256 + threadIdx.x;
    const int total = B_ * HW_;
    if (t >= total * NCG) return;
    int cgi = t / total;            // consecutive t -> same cgi, consecutive pix
    int pix = t - cgi * total;
    int x = pix % W_;
    int r = pix / W_;
    int y = r % H_;
    int b = r / H_;
    int tx = x / TS, ty = y / TS;
    int px = x - tx * TS, py = y - ty * TS;
    bool rl = px < R, rr = px >= TS - R;
    bool rt = py < R, rb = py >= TS - R;
    if (!(rl | rr | rt | rb)) return;

    int dx = rl ? -1 : (rr ? 1 : 0);
    int dy = rt ? -1 : (rb ? 1 : 0);

    int t_h = -1, c_h = 0, t_v = -1, c_v = 0, t_d = -1, c_d = 0;
    if (dx) {
        int ntx = tx + dx;
        if ((unsigned)ntx < TILES_X) {
            t_h = ty * TILES_X + ntx;
            c_h = halo_cell(y - (ty * TS - R), x - (ntx * TS - R));
        }
    }
    if (dy) {
        int nty = ty + dy;
        if ((unsigned)nty < TILES_Y) {
            t_v = nty * TILES_X + tx;
            c_v = halo_cell(y - (nty * TS - R), x - (tx * TS - R));
        }
    }
    if (dx && dy) {
        int ntx = tx + dx, nty = ty + dy;
        if ((unsigned)ntx < TILES_X && (unsigned)nty < TILES_Y) {
            t_d = nty * TILES_X + ntx;
            c_d = halo_cell(y - (nty * TS - R), x - (ntx * TS - R));
        }
    }
    if (t_h < 0 && t_v < 0 && t_d < 0) return;

    size_t o = (size_t)y * W_ + x;
    #pragma unroll
    for (int cc = 0; cc < CG; ++cc) {
        int c = cgi * CG + cc;
        size_t cb = (size_t)(b * C_ + c);
        float s = out[cb * HW_ + o];
        if (t_h >= 0) s += buf[(cb * NTILES + t_h) * HALO_CELLS + c_h];
        if (t_v >= 0) s += buf[(cb * NTILES + t_v) * HALO_CELLS + c_v];
        if (t_d >= 0) s += buf[(cb * NTILES + t_d) * HALO_CELLS + c_d];
        out[cb * HW_ + o] = s;
    }
}

// Far kernel: replay pixels whose window predicate failed (native atomics).
__global__ __launch_bounds__(256)
void fw_warp_far(const float* __restrict__ im0,
                 const float* __restrict__ flow,
                 float* __restrict__ out) {
    int tid = blockIdx.x * blockDim.x + threadIdx.x;
    const int total = B_ * HW_;
    if (tid >= total) return;
    int x = tid % W_;
    int t = tid / W_;
    int y = t % H_;
    int b = t / H_;

    float2 f = ((const float2*)flow)[tid];
    float xf = (float)x + f.x;
    float yf = (float)y + f.y;
    float x0f = floorf(xf), y0f = floorf(yf);
    int x0 = (int)x0f, y0 = (int)y0f;
    int tx0 = (x / TS) * TS;
    int ty0 = (y / TS) * TS;
    bool inwin = !(x0 < tx0 - R || x0 > tx0 + TS + R - 2 ||
                   y0 < ty0 - R || y0 > ty0 + TS + R - 2);
    if (inwin) return;   // tiled kernel handled it

    float wx1 = xf - x0f, wx0 = 1.0f - wx1;
    float wy1 = yf - y0f, wy0 = 1.0f - wy1;
    bool xv0 = (unsigned)x0       < (unsigned)W_;
    bool xv1 = (unsigned)(x0 + 1) < (unsigned)W_;
    bool yv0 = (unsigned)y0       < (unsigned)H_;
    bool yv1 = (unsigned)(y0 + 1) < (unsigned)H_;

    for (int c = 0; c < C_; ++c) {
        float v = im0[(size_t)(b * C_ + c) * HW_ + (size_t)y * W_ + x];
        float* op = out + (size_t)(b * C_ + c) * HW_;
        if (yv0 && xv0) fadd_glb(&op[(size_t)y0 * W_ + x0],           v * wx0 * wy0);
        if (yv0 && xv1) fadd_glb(&op[(size_t)y0 * W_ + x0 + 1],       v * wx1 * wy0);
        if (yv1 && xv0) fadd_glb(&op[(size_t)(y0 + 1) * W_ + x0],     v * wx0 * wy1);
        if (yv1 && xv1) fadd_glb(&op[(size_t)(y0 + 1) * W_ + x0 + 1], v * wx1 * wy1);
    }
}

// Replay kernel: bin-overflow pixels, per (pixel, cg) entry; native atomics.
// Runs LAST (after all plain stores and halo-gather RMW).
__global__ __launch_bounds__(256)
void fw_warp_replay(const float* __restrict__ im0,
                    const float* __restrict__ flow,
                    float* __restrict__ out,
                    const unsigned* __restrict__ ovctr,
                    const unsigned* __restrict__ ovlist,
                    unsigned cap) {
    unsigned n = *ovctr;
    if (n > cap) n = cap;
    unsigned t = blockIdx.x * 256 + threadIdx.x;
    if (t >= n) return;
    unsigned e = ovlist[t];
    int cg = (int)(e >> 24);
    unsigned gid = e & 0xFFFFFFu;
    int b = gid / HW_;
    int rem = gid - b * HW_;
    int y = rem / W_, x = rem - (rem / W_) * W_;

    float2 f = ((const float2*)flow)[gid];
    float xf = (float)x + f.x;
    float yf = (float)y + f.y;
    float x0f = floorf(xf), y0f = floorf(yf);
    int x0 = (int)x0f, y0 = (int)y0f;
    float wx1 = xf - x0f, wx0 = 1.0f - wx1;
    float wy1 = yf - y0f, wy0 = 1.0f - wy1;
    bool xv0 = (unsigned)x0       < (unsigned)W_;
    bool xv1 = (unsigned)(x0 + 1) < (unsigned)W_;
    bool yv0 = (unsigned)y0       < (unsigned)H_;
    bool yv1 = (unsigned)(y0 + 1) < (unsigned)H_;

    for (int cc = 0; cc < CG; ++cc) {
        int c = cg * CG + cc;
        float v = im0[(size_t)(b * C_ + c) * HW_ + (size_t)y * W_ + x];
        float* op = out + (size_t)(b * C_ + c) * HW_;
        if (yv0 && xv0) fadd_glb(&op[(size_t)y0 * W_ + x0],           v * wx0 * wy0);
        if (yv0 && xv1) fadd_glb(&op[(size_t)y0 * W_ + x0 + 1],       v * wx1 * wy0);
        if (yv1 && xv0) fadd_glb(&op[(size_t)(y0 + 1) * W_ + x0],     v * wx0 * wy1);
        if (yv1 && xv1) fadd_glb(&op[(size_t)(y0 + 1) * W_ + x0 + 1], v * wx1 * wy1);
    }
}

// Legacy fallback (ws too small): direct LDS fp-atomic splat + atomic ring
// flush (round-2 structure). Correct but slow; out must be pre-zeroed.
__global__ __launch_bounds__(NT1)
void fw_warp_legacy(const float* __restrict__ im0,
                    const float* __restrict__ flow,
                    float* __restrict__ out) {
    __shared__ float acc[CG * WIN * WIN];
    const int cg = blockIdx.x, tI = blockIdx.y, b = blockIdx.z;
    const int tx0 = (tI % TILES_X) * TS;
    const int ty0 = (tI / TILES_X) * TS;
    const int tid = threadIdx.x;
    for (int i = tid; i < CG * WIN * WIN; i += NT1) acc[i] = 0.0f;
    __syncthreads();
    const float*  imp = im0 + (size_t)(b * C_ + cg * CG) * HW_;
    const float2* flp = (const float2*)flow + (size_t)b * HW_;
    for (int i = tid; i < TS * TS; i += NT1) {
        int py = i / TS, px = i - py * TS;
        int y = ty0 + py, x = tx0 + px;
        if (x >= W_) continue;
        float2 f = flp[y * W_ + x];
        float xf = (float)x + f.x, yf = (float)y + f.y;
        float x0f = floorf(xf), y0f = floorf(yf);
        int x0 = (int)x0f, y0 = (int)y0f;
        if (x0 < tx0 - R || x0 > tx0 + TS + R - 2 ||
            y0 < ty0 - R || y0 > ty0 + TS + R - 2) continue;
        float wx1 = xf - x0f, wx0 = 1.0f - wx1;
        float wy1 = yf - y0f, wy0 = 1.0f - wy1;
        float w00 = wx0 * wy0, w10 = wx1 * wy0;
        float w01 = wx0 * wy1, w11 = wx1 * wy1;
        const float* ip = imp + (size_t)y * W_ + x;
        int lx = x0 - (tx0 - R), ly = y0 - (ty0 - R);
        float* p = &acc[ly * WIN + lx];
        #pragma unroll
        for (int cc = 0; cc < CG; ++cc) {
            float v = ip[cc * HW_];
            atomicAdd(p,           v * w00);
            atomicAdd(p + 1,       v * w10);
            atomicAdd(p + WIN,     v * w01);
            atomicAdd(p + WIN + 1, v * w11);
            p += WIN * WIN;
        }
    }
    __syncthreads();
    float* outp = out + (size_t)(b * C_ + cg * CG) * HW_;
    for (int i = tid; i < WIN * WIN; i += NT1) {
        int wy = i / WIN, wx = i - wy * WIN;
        int gy = ty0 - R + wy, gx = tx0 - R + wx;
        if ((unsigned)gy < (unsigned)H_ && (unsigned)gx < (unsigned)W_) {
            bool interior = (wy >= 2 * R) && (wy < TS) && (wx >= 2 * R) && (wx < TS);
            size_t o = (size_t)gy * W_ + gx;
            #pragma unroll
            for (int c = 0; c < CG; ++c) {
                float v = acc[c * WIN * WIN + i];
                if (interior)          outp[(size_t)c * HW_ + o] = v;
                else if (v != 0.0f)    fadd_glb(&outp[(size_t)c * HW_ + o], v);
            }
        }
    }
}

extern "C" void kernel_launch(void* const* d_in, const int* in_sizes, int n_in,
                              void* d_out, int out_size, void* d_ws, size_t ws_size,
                              hipStream_t stream) {
    const float* im0  = (const float*)d_in[0];
    const float* flow = (const float*)d_in[1];
    float* out = (float*)d_out;

    const size_t HALO_BYTES = (size_t)B_ * C_ * NTILES * HALO_CELLS * sizeof(float); // 95.2 MB
    const int totalPix = B_ * HW_;
    dim3 grid1(NCG, NTILES, B_);

    const unsigned CAP_BIG = 262144, CAP_SMALL = 16384;
    unsigned cap = 0;
    if (d_ws && ws_size >= HALO_BYTES + 64 + CAP_BIG * 4)        cap = CAP_BIG;
    else if (d_ws && ws_size >= HALO_BYTES + 64 + CAP_SMALL * 4) cap = CAP_SMALL;

    if (cap) {
        unsigned* ovctr  = (unsigned*)((char*)d_ws + HALO_BYTES);
        unsigned* ovlist = ovctr + 16;
        hipMemsetAsync(ovctr, 0, sizeof(unsigned), stream);
        fw_warp_bin<<<grid1, NT1, 0, stream>>>(im0, flow, out, (float*)d_ws,
                                               ovctr, ovlist, cap);
        fw_warp_hgather<<<(totalPix * NCG + 255) / 256, 256, 0, stream>>>(
            (const float*)d_ws, out);
        fw_warp_far<<<(totalPix + 255) / 256, 256, 0, stream>>>(im0, flow, out);
        fw_warp_replay<<<(cap + 255) / 256, 256, 0, stream>>>(im0, flow, out,
                                                              ovctr, ovlist, cap);
    } else {
        hipMemsetAsync(d_out, 0, (size_t)out_size * sizeof(float), stream);
        fw_warp_legacy<<<grid1, NT1, 0, stream>>>(im0, flow, out);
        fw_warp_far<<<(totalPix + 255) / 256, 256, 0, stream>>>(im0, flow, out);
    }
}